// Round 6
// baseline (1733.951 us; speedup 1.0000x reference)
//
#include <hip/hip_runtime.h>

// Att_RNN_GRU: B=128, T=1024, I=128, H=256 (3H=768), A=40
// Phase 1: gx = x @ W_ih^T + b_ih (+b_hh for r,z)  -> f16 [B*T,768]  (MFMA GEMM)
// Phase 2: GRU recurrence, 1 block/batch (128 CUs), 1024 thr (16 waves, 4/SIMD):
//          thread (g=tid>>2, qs=tid&3) owns rows {g,g+256,g+512}, k-quarter qs.
//          w register-resident 96 dwords; h in LDS quarters padded 144B apart
//          (4 bcast addresses at banks {0,4,8,12} -> conflict-free); reduce =
//          quad butterfly (2 DPP) so all 4 lanes hold sums -> gate math fully
//          parallel. ONE barrier/step. h_t overwrites gx row (b,t)[0:256].
// Phase 3a: s[b,t] = wu . tanh(wv_W @ out + wv_b)   (outs = gx rows, stride 768)
// Phase 3b: softmax over t, context, out = context @ h2o_W^T + b
//
// Workspace: s @0 (512KB), Wp @524288 (384KB), gx @917504 (192MB) = 202.2MB

#define B_ 128
#define T_ 1024
#define I_ 128
#define H_ 256
#define G_ 768
#define A_ 40

typedef _Float16 f16;
typedef _Float16 f16x2 __attribute__((ext_vector_type(2)));
typedef _Float16 f16x8 __attribute__((ext_vector_type(8)));
typedef float    f32x4 __attribute__((ext_vector_type(4)));

__device__ __forceinline__ float fdot2(unsigned a, unsigned b, float c){
#if __has_builtin(__builtin_amdgcn_fdot2)
  return __builtin_amdgcn_fdot2(__builtin_bit_cast(f16x2, a),
                                __builtin_bit_cast(f16x2, b), c, false);
#else
  f16x2 av = __builtin_bit_cast(f16x2, a), bv = __builtin_bit_cast(f16x2, b);
  return c + (float)av.x * (float)bv.x + (float)av.y * (float)bv.y;
#endif
}

__device__ __forceinline__ float2 h2f(unsigned u){
  f16x2 h = __builtin_bit_cast(f16x2, u);
  return make_float2((float)h.x, (float)h.y);
}
__device__ __forceinline__ unsigned f2h2(float a, float b){
  f16x2 h; h.x = (f16)a; h.y = (f16)b;
  return __builtin_bit_cast(unsigned, h);
}
__device__ __forceinline__ float sigm_(float x){ return 1.f / (1.f + __expf(-x)); }
__device__ __forceinline__ float tanh_(float x){ return 1.f - 2.f / (__expf(2.f * x) + 1.f); }

// butterfly sum over a quad (lanes x^1 then x^2): all 4 lanes get the total.
__device__ __forceinline__ float quad_sum(float x){
  int t = __builtin_amdgcn_update_dpp(0, __builtin_bit_cast(int, x),
                                      0xB1, 0xF, 0xF, true);   // quad_perm 1,0,3,2
  x += __builtin_bit_cast(float, t);
  t = __builtin_amdgcn_update_dpp(0, __builtin_bit_cast(int, x),
                                  0x4E, 0xF, 0xF, true);       // quad_perm 2,3,0,1
  return x + __builtin_bit_cast(float, t);
}

// ---------------------------------------------------------------- prep W_hh
// Wp[(c*32+d)*1024 + col] = f16 pair of W[c*256 + (col>>2)][(col&3)*64 + 2d .. +1]
// so k_gru thread `col` loads its 96 w-dwords fully coalesced.
__global__ __launch_bounds__(256) void k_prep_w(const float* __restrict__ W,
                                                unsigned* __restrict__ Wp){
  int idx = blockIdx.x * 256 + threadIdx.x;      // 0 .. 98303
  int dd  = idx >> 10;                           // 0..95 = c*32+d
  int col = idx & 1023;                          // k_gru tid
  int c = dd >> 5, d = dd & 31;
  int g = col >> 2, qs = col & 3;
  int r = c * 256 + g;
  int k = qs * 64 + 2 * d;
  Wp[(size_t)dd * 1024 + col] = f2h2(W[r * 256 + k], W[r * 256 + k + 1]);
}

// ---------------------------------------------------------------- phase 1
// MFMA GEMM: gx[m][n] = sum_k x[m][k]*W_ih[n][k] + b_ih[n] + (n<512 ? b_hh[n]:0)
__global__ __launch_bounds__(256) void k_gx(const float* __restrict__ x,
                                            const float* __restrict__ wih,
                                            const float* __restrict__ bih,
                                            const float* __restrict__ bhh,
                                            f16* __restrict__ gx){
  __shared__ __align__(16) f16 XA[128 * 128];   // [m][k], byte ^= (m&7)<<4
  __shared__ __align__(16) f16 XB[64 * 128];    // [n][k], same swizzle
  const int tid = threadIdx.x;
  const int m0 = blockIdx.x * 128, n0 = blockIdx.y * 64;

  #pragma unroll
  for (int u = 0; u < 16; ++u){
    int idx = tid + 256 * u;
    int row = idx >> 5, k4 = idx & 31;
    float4 v = *(const float4*)(x + (size_t)(m0 + row) * I_ + k4 * 4);
    unsigned byte = (unsigned)(row * 256 + k4 * 8) ^ ((row & 7) << 4);
    *(uint2*)((char*)XA + byte) = make_uint2(f2h2(v.x, v.y), f2h2(v.z, v.w));
  }
  #pragma unroll
  for (int u = 0; u < 8; ++u){
    int idx = tid + 256 * u;
    int row = idx >> 5, k4 = idx & 31;
    float4 v = *(const float4*)(wih + (size_t)(n0 + row) * I_ + k4 * 4);
    unsigned byte = (unsigned)(row * 256 + k4 * 8) ^ ((row & 7) << 4);
    *(uint2*)((char*)XB + byte) = make_uint2(f2h2(v.x, v.y), f2h2(v.z, v.w));
  }
  __syncthreads();

  const int l = tid & 63, w = tid >> 6;
  const int q = l >> 4, m16 = l & 15;
  f32x4 acc[2][4];
  #pragma unroll
  for (int i = 0; i < 2; ++i)
    #pragma unroll
    for (int nt = 0; nt < 4; ++nt) acc[i][nt] = (f32x4){0.f, 0.f, 0.f, 0.f};

  #pragma unroll
  for (int kt = 0; kt < 4; ++kt){
    f16x8 af[2];
    #pragma unroll
    for (int i = 0; i < 2; ++i){
      int row = (2 * w + i) * 16 + m16;
      unsigned byte = (unsigned)(row * 256 + kt * 64 + q * 16) ^ ((row & 7) << 4);
      af[i] = *(const f16x8*)((const char*)XA + byte);
    }
    #pragma unroll
    for (int nt = 0; nt < 4; ++nt){
      int row = nt * 16 + m16;
      unsigned byte = (unsigned)(row * 256 + kt * 64 + q * 16) ^ ((row & 7) << 4);
      f16x8 bv = *(const f16x8*)((const char*)XB + byte);
      acc[0][nt] = __builtin_amdgcn_mfma_f32_16x16x32_f16(af[0], bv, acc[0][nt], 0, 0, 0);
      acc[1][nt] = __builtin_amdgcn_mfma_f32_16x16x32_f16(af[1], bv, acc[1][nt], 0, 0, 0);
    }
  }

  float bn[4];
  #pragma unroll
  for (int nt = 0; nt < 4; ++nt){
    int n = n0 + nt * 16 + m16;
    bn[nt] = bih[n] + (n < 512 ? bhh[n] : 0.f);
  }

  __syncthreads();
  f16* ST = XA;                                  // reuse as [128][72]
  #pragma unroll
  for (int i = 0; i < 2; ++i)
    #pragma unroll
    for (int nt = 0; nt < 4; ++nt)
      #pragma unroll
      for (int j = 0; j < 4; ++j){
        int row = (2 * w + i) * 16 + 4 * q + j;
        ST[row * 72 + nt * 16 + m16] = (f16)(acc[i][nt][j] + bn[nt]);
      }
  __syncthreads();
  #pragma unroll
  for (int u = 0; u < 4; ++u){
    int idx = tid + 256 * u;
    int row = idx >> 3, c = idx & 7;
    uint4 v = *(const uint4*)(ST + row * 72 + c * 8);
    *(uint4*)(gx + (size_t)(m0 + row) * G_ + n0 + c * 8) = v;
  }
}

// ---------------------------------------------------------------- phase 2
// 128 blocks x 1024 threads (16 waves, 4/SIMD).
__global__ __launch_bounds__(1024, 4) void k_gru(const unsigned* __restrict__ Wp,
                                                 unsigned* __restrict__ gx,
                                                 const float* __restrict__ bhh){
  __shared__ uint4 hb[2][4][9];   // [buf][quarter][8 uint4 + 1 pad]
  const int tid = threadIdx.x;
  const int g = tid >> 2, qs = tid & 3;
  const int b = blockIdx.x;

  unsigned w0[32], w1[32], w2[32];
  #pragma unroll
  for (int d = 0; d < 32; ++d) w0[d] = Wp[(size_t)(d     ) * 1024 + tid];
  #pragma unroll
  for (int d = 0; d < 32; ++d) w1[d] = Wp[(size_t)(32 + d) * 1024 + tid];
  #pragma unroll
  for (int d = 0; d < 32; ++d) w2[d] = Wp[(size_t)(64 + d) * 1024 + tid];

  const float bn_ = bhh[512 + g];
  float hprev = 0.f;
  if (tid < 72) ((uint4*)hb)[tid] = make_uint4(0, 0, 0, 0);

  f16* gxp = (f16*)gx + (size_t)b * T_ * G_;
  float xr = (float)gxp[g], xz = (float)gxp[H_ + g], xn = (float)gxp[2 * H_ + g];
  __syncthreads();

  int cur = 0;
  for (int t = 0; t < T_; ++t){
    float pr = 0.f, pz = 0.f, pn = 0.f;          // prefetch t+1 x-terms
    if (t + 1 < T_){
      const f16* nx = gxp + (size_t)(t + 1) * G_;
      pr = (float)nx[g]; pz = (float)nx[H_ + g]; pn = (float)nx[2 * H_ + g];
    }

    float a0 = 0.f, b0 = 0.f, a1 = 0.f, b1 = 0.f, a2 = 0.f, b2 = 0.f;
    #pragma unroll
    for (int i = 0; i < 8; ++i){
      uint4 hv = hb[cur][qs][i];
      a0 = fdot2(w0[4*i+0], hv.x, a0); b0 = fdot2(w0[4*i+1], hv.y, b0);
      a0 = fdot2(w0[4*i+2], hv.z, a0); b0 = fdot2(w0[4*i+3], hv.w, b0);
      a1 = fdot2(w1[4*i+0], hv.x, a1); b1 = fdot2(w1[4*i+1], hv.y, b1);
      a1 = fdot2(w1[4*i+2], hv.z, a1); b1 = fdot2(w1[4*i+3], hv.w, b1);
      a2 = fdot2(w2[4*i+0], hv.x, a2); b2 = fdot2(w2[4*i+1], hv.y, b2);
      a2 = fdot2(w2[4*i+2], hv.z, a2); b2 = fdot2(w2[4*i+3], hv.w, b2);
    }
    float ar = quad_sum(a0 + b0);
    float az = quad_sum(a1 + b1);
    float an = quad_sum(a2 + b2);

    // all 4 lanes of the quad compute gates (redundant, no divergence)
    float rg = sigm_(xr + ar);                   // b_hh(r,z) folded into gx
    float zg = sigm_(xz + az);
    float ng = tanh_(xn + rg * (an + bn_));
    float h  = (1.f - zg) * ng + zg * hprev;
    hprev = h;
    if (qs == 0){
      f16 hh = (f16)h;
      ((f16*)&hb[cur ^ 1][g >> 6][0])[g & 63] = hh;  // h for next step
      gxp[(size_t)t * G_ + g] = hh;                  // overwrite consumed gx row
    }
    xr = pr; xz = pz; xn = pn;
    __syncthreads();
    cur ^= 1;
  }
}

// ---------------------------------------------------------------- phase 3a
__global__ __launch_bounds__(256) void k_score(const f16* __restrict__ outs,
                                               const float* __restrict__ wvW,
                                               const float* __restrict__ wvb,
                                               const float* __restrict__ wu,
                                               float* __restrict__ s){
  __shared__ uint4 OT[32 * 33];
  __shared__ float WV[A_ * 260];
  const int tid = threadIdx.x;
  const int m0 = blockIdx.x * 32;

  #pragma unroll
  for (int u = 0; u < 4; ++u){
    int idx = tid + 256 * u;
    int row = idx >> 5, col = idx & 31;
    OT[row * 33 + col] = *(const uint4*)(outs + (size_t)(m0 + row) * G_ + col * 8);
  }
  #pragma unroll
  for (int u = 0; u < 10; ++u){
    int f = tid + 256 * u;
    int a = f >> 6, k4 = f & 63;
    float4 v = *(const float4*)(wvW + a * 256 + k4 * 4);
    *(float4*)(WV + a * 260 + k4 * 4) = v;
  }
  __syncthreads();

  const int m = tid >> 3, aq = tid & 7;
  float acc[5] = {0.f, 0.f, 0.f, 0.f, 0.f};
  for (int i = 0; i < 32; ++i){
    uint4 oc = OT[m * 33 + i];
    float2 o01 = h2f(oc.x), o23 = h2f(oc.y), o45 = h2f(oc.z), o67 = h2f(oc.w);
    #pragma unroll
    for (int sa = 0; sa < 5; ++sa){
      int a = aq + sa * 8;
      const float* wr = &WV[a * 260 + i * 8];
      float4 w0 = *(const float4*)wr;
      float4 w1 = *(const float4*)(wr + 4);
      acc[sa] += o01.x*w0.x + o01.y*w0.y + o23.x*w0.z + o23.y*w0.w
               + o45.x*w1.x + o45.y*w1.y + o67.x*w1.z + o67.y*w1.w;
    }
  }
  float sp = 0.f;
  #pragma unroll
  for (int sa = 0; sa < 5; ++sa){
    int a = aq + sa * 8;
    sp += wu[a] * tanh_(acc[sa] + wvb[a]);
  }
  sp += __shfl_xor(sp, 1);
  sp += __shfl_xor(sp, 2);
  sp += __shfl_xor(sp, 4);
  if (aq == 0) s[m0 + m] = sp;
}

// ---------------------------------------------------------------- phase 3b
__global__ __launch_bounds__(256) void k_ctx(const f16* __restrict__ outs,
                                             const float* __restrict__ s,
                                             const float* __restrict__ h2oW,
                                             const float* __restrict__ h2ob,
                                             float* __restrict__ out){
  __shared__ float AL[T_];
  __shared__ float red[8];
  const int tid = threadIdx.x;
  const int b = blockIdx.x;
  const float* sb = s + (size_t)b * T_;

  float v0 = sb[tid], v1 = sb[tid + 256], v2 = sb[tid + 512], v3 = sb[tid + 768];
  float mx = fmaxf(fmaxf(v0, v1), fmaxf(v2, v3));
  #pragma unroll
  for (int msk = 1; msk < 64; msk <<= 1) mx = fmaxf(mx, __shfl_xor(mx, msk));
  if ((tid & 63) == 0) red[tid >> 6] = mx;
  __syncthreads();
  mx = fmaxf(fmaxf(red[0], red[1]), fmaxf(red[2], red[3]));

  float e0 = __expf(v0 - mx), e1 = __expf(v1 - mx), e2 = __expf(v2 - mx), e3 = __expf(v3 - mx);
  float zs = e0 + e1 + e2 + e3;
  #pragma unroll
  for (int msk = 1; msk < 64; msk <<= 1) zs += __shfl_xor(zs, msk);
  if ((tid & 63) == 0) red[4 + (tid >> 6)] = zs;
  __syncthreads();
  float invZ = 1.f / (red[4] + red[5] + red[6] + red[7]);
  AL[tid] = e0 * invZ; AL[tid + 256] = e1 * invZ;
  AL[tid + 512] = e2 * invZ; AL[tid + 768] = e3 * invZ;
  __syncthreads();

  const f16* ob = outs + (size_t)b * T_ * G_;
  float acc = 0.f;
  for (int t = 0; t < T_; t += 4){
    acc += AL[t + 0] * (float)ob[(size_t)(t + 0) * G_ + tid];
    acc += AL[t + 1] * (float)ob[(size_t)(t + 1) * G_ + tid];
    acc += AL[t + 2] * (float)ob[(size_t)(t + 2) * G_ + tid];
    acc += AL[t + 3] * (float)ob[(size_t)(t + 3) * G_ + tid];
  }
  __syncthreads();
  float val = acc * h2oW[tid];
  #pragma unroll
  for (int msk = 1; msk < 64; msk <<= 1) val += __shfl_xor(val, msk);
  if ((tid & 63) == 0) red[tid >> 6] = val;
  __syncthreads();
  if (tid == 0) out[b] = red[0] + red[1] + red[2] + red[3] + h2ob[0];
}

// ---------------------------------------------------------------- launch
extern "C" void kernel_launch(void* const* d_in, const int* in_sizes, int n_in,
                              void* d_out, int out_size, void* d_ws, size_t ws_size,
                              hipStream_t stream){
  const float* x    = (const float*)d_in[0];
  const float* wih  = (const float*)d_in[1];
  const float* whh  = (const float*)d_in[2];
  const float* bih  = (const float*)d_in[3];
  const float* bhh  = (const float*)d_in[4];
  const float* wvW  = (const float*)d_in[5];
  const float* wvb  = (const float*)d_in[6];
  const float* wu   = (const float*)d_in[7];
  const float* h2oW = (const float*)d_in[8];
  const float* h2ob = (const float*)d_in[9];
  float* out = (float*)d_out;

  char* ws = (char*)d_ws;
  float*    s  = (float*)ws;                      //     524,288 B
  unsigned* Wp = (unsigned*)(ws + 524288);        //     393,216 B
  unsigned* gx = (unsigned*)(ws + 917504);        // 201,326,592 B

  k_prep_w<<<384, 256, 0, stream>>>(whh, Wp);
  k_gx<<<dim3((B_ * T_) / 128, G_ / 64), 256, 0, stream>>>(x, wih, bih, bhh, (f16*)gx);
  k_gru<<<B_, 1024, 0, stream>>>(Wp, gx, bhh);
  k_score<<<(B_ * T_) / 32, 256, 0, stream>>>((const f16*)gx, wvW, wvb, wu, s);
  k_ctx<<<B_, 256, 0, stream>>>((const f16*)gx, s, h2oW, h2ob, out);
}